// Round 7
// baseline (68.348 us; speedup 1.0000x reference)
//
#include <hip/hip_runtime.h>
#include <hip/hip_bf16.h>

#define NB 4
#define SEQ 4096
#define CDIM 768
#define HD 48

typedef __attribute__((ext_vector_type(8))) __bf16 bf16x8;
typedef __attribute__((ext_vector_type(16))) float f32x16;

// (1/sqrt(48)) * log2(e): folded into Q at projection store so P = exp2(S_acc)
static constexpr float SCALE_LOG2E = 0.20823542135164923f;

__device__ __forceinline__ bf16x8 ldg8(const __hip_bfloat16* p) {
    uint4 u = *reinterpret_cast<const uint4*>(p);
    bf16x8 r;
    __builtin_memcpy(&r, &u, 16);
    return r;
}
__device__ __forceinline__ unsigned pk2(float lo, float hi) {
    const __hip_bfloat16 a = __float2bfloat16(lo);
    const __hip_bfloat16 b = __float2bfloat16(hi);
    unsigned short ua, ub;
    __builtin_memcpy(&ua, &a, 2);
    __builtin_memcpy(&ub, &b, 2);
    return (unsigned)ua | ((unsigned)ub << 16);
}
__device__ __forceinline__ bf16x8 mk8(unsigned w0, unsigned w1, unsigned w2, unsigned w3) {
    const uint4 u = make_uint4(w0, w1, w2, w3);
    bf16x8 r;
    __builtin_memcpy(&r, &u, 16);
    return r;
}
// a,b -> a=[a.lo|b.lo], b=[a.hi|b.hi]  (swap a's upper 32 lanes with b's lower)
__device__ __forceinline__ void plswap(unsigned& a, unsigned& b) {
    asm volatile("v_permlane32_swap_b32 %0, %1" : "+v"(a), "+v"(b));
}
// Q/K fragment base offset (elements): frag (tile, s, h) is 256 contiguous bf16
__device__ __forceinline__ size_t fragOff(int tile, int s, int h) {
    return (((size_t)tile * 3 + s) * 2 + h) * 256;
}

// ---------------------------------------------------------------------------
// Kernel 0: prep — Wf in B-fragment-major layout:
//   Wf[nt(5)][ks(48)][l(64)][8] bf16, elem (nt,ks,l,j) = W[ks*16+(l>>5)*8+j][nt*32+(l&31)]
//   cols: 0..47 = Wq, 48..95 = Wk, 96..143 = Wv, 144..159 = 0.  bias[160].
// ---------------------------------------------------------------------------
__global__ __launch_bounds__(256) void prep_kernel(
    const float* __restrict__ Wq, const float* __restrict__ Wk,
    const float* __restrict__ Wv,
    const float* __restrict__ bq, const float* __restrict__ bk,
    const float* __restrict__ bv,
    __hip_bfloat16* __restrict__ Wf, float* __restrict__ bias)
{
    const int g = blockIdx.x * 256 + threadIdx.x;   // 0..15359
    if (g < 15360) {
        const int rem  = g % 3072;
        const int nt   = g / 3072;
        const int ks   = rem >> 6;
        const int l2   = rem & 63;
        const int hh   = l2 >> 5;
        const int lane = l2 & 31;
        const int n    = nt * 32 + lane;
        const float* src = (n < 48) ? Wq : (n < 96) ? Wk : (n < 144) ? Wv : nullptr;
        const int col = (n < 48) ? n : (n < 96) ? (n - 48) : (n - 96);
        #pragma unroll
        for (int j = 0; j < 8; ++j) {
            const int k = ks * 16 + hh * 8 + j;
            const float wv = src ? src[(size_t)k * HD + col] : 0.0f;
            Wf[(size_t)g * 8 + j] = __float2bfloat16(wv);
        }
    }
    if (blockIdx.x == 0 && threadIdx.x < 160) {
        const int t = threadIdx.x;
        bias[t] = (t < 48) ? bq[t] : (t < 96) ? bk[t - 48] : (t < 144) ? bv[t - 96] : 0.0f;
    }
}

// ---------------------------------------------------------------------------
// Kernel 1: proj.  1 block per 32-row m-tile, 5 waves (wave = one 32-col n-tile).
// Stage x rows coalesced-along-k -> A-frag-major LDS (bf16), then
// 48 x { ds_read_b128 A + coalesced global B + MFMA }.
// ---------------------------------------------------------------------------
__global__ __launch_bounds__(320) void proj_kernel(
    const float* __restrict__ x,
    const __hip_bfloat16* __restrict__ Wf, const float* __restrict__ bias,
    __hip_bfloat16* __restrict__ Qf, __hip_bfloat16* __restrict__ Kf,
    float* __restrict__ Vf)
{
    __shared__ __hip_bfloat16 xs[48 * 512];   // [ks][l][8] frag-major, 48 KB

    const int t   = threadIdx.x;
    const int w   = t >> 6;          // wave = n-tile 0..4
    const int l   = t & 63;
    const int lo5 = l & 31, h = l >> 5;
    const int mt  = blockIdx.x;      // 0..511
    const int m0  = mt * 32;

    // stage: 32 rows x 768 k fp32 -> bf16 frag-major.  6144 float4 over 320 thr.
    const float* xb = x + (size_t)m0 * CDIM;
    #pragma unroll
    for (int i = 0; i < 20; ++i) {
        const int c = i * 320 + t;
        if (c < 6144) {
            const int r   = c / 192;
            const int pos = c % 192;
            const int k   = pos * 4;
            const float4 v = *reinterpret_cast<const float4*>(xb + (size_t)r * CDIM + k);
            const int ks = k >> 4, hh = (k >> 3) & 1, j = k & 7;
            const uint2 d = make_uint2(pk2(v.x, v.y), pk2(v.z, v.w));
            *reinterpret_cast<uint2*>(&xs[ks * 512 + (hh * 32 + r) * 8 + j]) = d;
        }
    }
    __syncthreads();

    const __hip_bfloat16* bp = Wf + (size_t)w * 24576 + l * 8;
    f32x16 acc = {};
    #pragma unroll 8
    for (int ks = 0; ks < 48; ++ks) {
        bf16x8 a;
        __builtin_memcpy(&a, &xs[ks * 512 + l * 8], 16);
        const bf16x8 b = ldg8(bp + (size_t)ks * 512);
        __builtin_amdgcn_s_setprio(1);
        acc = __builtin_amdgcn_mfma_f32_32x32x16_bf16(a, b, acc, 0, 0, 0);
        __builtin_amdgcn_s_setprio(0);
    }

    const int n_g = w * 32 + lo5;
    const float bs = bias[n_g];
    if (n_g < 96) {
        const bool isQ = (n_g < 48);
        const int d  = isQ ? n_g : n_g - 48;
        const int s  = d >> 4;
        const int hf = (d >> 3) & 1;
        __hip_bfloat16* base = (isQ ? Qf : Kf) + fragOff(mt, s, hf) + (d & 7);
        #pragma unroll
        for (int r = 0; r < 16; ++r) {
            const int mrow = (r & 3) + 8 * (r >> 2) + 4 * h;
            float val = acc[r] + bs;
            if (isQ) val *= SCALE_LOG2E;
            base[mrow * 8] = __float2bfloat16(val);
        }
    } else if (n_g < 144) {
        const int d = n_g - 96;
        #pragma unroll
        for (int r = 0; r < 16; ++r) {
            const int m = m0 + (r & 3) + 8 * (r >> 2) + 4 * h;
            Vf[(size_t)m * HD + d] = acc[r] + bs;
        }
    }
}

// ---------------------------------------------------------------------------
// Kernel 2: column softmax denominator + V fold.  8 waves split the q-range.
// Vt tiled [b][ktile][d(64)][32] bf16 = V[k][d] / l_k  (d<48 written only).
// ---------------------------------------------------------------------------
__global__ __launch_bounds__(512) void stats_kernel(
    const __hip_bfloat16* __restrict__ Qf, const __hip_bfloat16* __restrict__ Kf,
    const float* __restrict__ Vf, __hip_bfloat16* __restrict__ Vt)
{
    __shared__ float part[8][32];
    __shared__ float linv[32];

    const int t   = threadIdx.x;
    const int w   = t >> 6;
    const int l   = t & 63;
    const int lo5 = l & 31, h = l >> 5;
    const int b       = blockIdx.y;
    const int ktile_l = blockIdx.x;             // 0..127
    const int ktile   = b * 128 + ktile_l;

    bf16x8 ka[3];
    #pragma unroll
    for (int s = 0; s < 3; ++s)
        ka[s] = ldg8(Kf + fragOff(ktile, s, h) + lo5 * 8);

    float lsum[16];
    #pragma unroll
    for (int r = 0; r < 16; ++r) lsum[r] = 0.0f;

    const int qt0 = b * 128 + w * 16;
    #pragma unroll 2
    for (int qq = 0; qq < 16; ++qq) {
        bf16x8 qb[3];
        #pragma unroll
        for (int s = 0; s < 3; ++s)
            qb[s] = ldg8(Qf + fragOff(qt0 + qq, s, h) + lo5 * 8);
        f32x16 acc = {};
        __builtin_amdgcn_s_setprio(1);
        #pragma unroll
        for (int s = 0; s < 3; ++s)
            acc = __builtin_amdgcn_mfma_f32_32x32x16_bf16(ka[s], qb[s], acc, 0, 0, 0);
        __builtin_amdgcn_s_setprio(0);
        #pragma unroll
        for (int r = 0; r < 16; ++r) lsum[r] += __builtin_amdgcn_exp2f(acc[r]);
    }

    #pragma unroll
    for (int r = 0; r < 16; ++r) {
        lsum[r] += __shfl_xor(lsum[r], 1);
        lsum[r] += __shfl_xor(lsum[r], 2);
        lsum[r] += __shfl_xor(lsum[r], 4);
        lsum[r] += __shfl_xor(lsum[r], 8);
        lsum[r] += __shfl_xor(lsum[r], 16);
    }
    if (lo5 == 0) {
        #pragma unroll
        for (int r = 0; r < 16; ++r)
            part[w][(r & 3) + 8 * (r >> 2) + 4 * h] = lsum[r];
    }
    __syncthreads();
    if (t < 32) {
        float s = 0.0f;
        #pragma unroll
        for (int p = 0; p < 8; ++p) s += part[p][t];
        linv[t] = 1.0f / s;
    }
    __syncthreads();

    // V fold: thread -> (k-pair kp, d = dg and dg+32 if dg<16)
    const int kp = t & 15;
    const int dg = t >> 4;          // 0..31
    const float f0 = linv[2 * kp], f1 = linv[2 * kp + 1];
    __hip_bfloat16* vtb = Vt + (size_t)ktile * 2048;
    const float* vfb = Vf + ((size_t)b * SEQ + ktile_l * 32 + 2 * kp) * HD;
    {
        const int d = dg;
        const float v0 = vfb[d], v1 = vfb[HD + d];
        *reinterpret_cast<unsigned*>(&vtb[d * 32 + 2 * kp]) = pk2(v0 * f0, v1 * f1);
    }
    if (dg < 16) {
        const int d = dg + 32;
        const float v0 = vfb[d], v1 = vfb[HD + d];
        *reinterpret_cast<unsigned*>(&vtb[d * 32 + 2 * kp]) = pk2(v0 * f0, v1 * f1);
    }
}

// ---------------------------------------------------------------------------
// Kernel 3: O[q,d] = sum_k exp2(Shat[q,k]) * Vt[d,k].  8 waves split k-range.
// Balanced reduction: all 8 waves dump partials to LDS, 512 threads each sum
// 8 partials for 4 output cells and write float4s directly.
// ---------------------------------------------------------------------------
__global__ __launch_bounds__(512) void pv_kernel(
    const __hip_bfloat16* __restrict__ Qf, const __hip_bfloat16* __restrict__ Kf,
    const __hip_bfloat16* __restrict__ Vt, float* __restrict__ out)
{
    __shared__ float red[8][32][64];   // 64 KB

    const int t   = threadIdx.x;
    const int w   = t >> 6;
    const int l   = t & 63;
    const int lo5 = l & 31, h = l >> 5;
    const int b       = blockIdx.y;
    const int qtile_l = blockIdx.x;
    const int qtile   = b * 128 + qtile_l;
    const int q0      = qtile_l * 32;

    bf16x8 qb[3];
    #pragma unroll
    for (int s = 0; s < 3; ++s)
        qb[s] = ldg8(Qf + fragOff(qtile, s, h) + lo5 * 8);

    f32x16 o0 = {}, o1 = {};
    const int kt0 = b * 128 + w * 16;

    #pragma unroll 2
    for (int kk = 0; kk < 16; ++kk) {
        const int ktg = kt0 + kk;
        bf16x8 ka[3];
        #pragma unroll
        for (int s = 0; s < 3; ++s)
            ka[s] = ldg8(Kf + fragOff(ktg, s, h) + lo5 * 8);
        f32x16 acc = {};
        __builtin_amdgcn_s_setprio(1);
        #pragma unroll
        for (int s = 0; s < 3; ++s)
            acc = __builtin_amdgcn_mfma_f32_32x32x16_bf16(ka[s], qb[s], acc, 0, 0, 0);
        __builtin_amdgcn_s_setprio(0);

        float p[16];
        #pragma unroll
        for (int r = 0; r < 16; ++r) p[r] = __builtin_amdgcn_exp2f(acc[r]);

        // pack row-pairs then swap halves across lane 32 with permlane32_swap:
        //   (w0,w2) = swap(x0,y0): w0=[x0.lo|y0.lo], w2=[x0.hi|y0.hi]
        unsigned w0 = pk2(p[0],  p[1]),  w1 = pk2(p[2],  p[3]);
        unsigned w2 = pk2(p[4],  p[5]),  w3 = pk2(p[6],  p[7]);
        unsigned w4 = pk2(p[8],  p[9]),  w5 = pk2(p[10], p[11]);
        unsigned w6 = pk2(p[12], p[13]), w7 = pk2(p[14], p[15]);
        plswap(w0, w2);
        plswap(w1, w3);
        plswap(w4, w6);
        plswap(w5, w7);

        const bf16x8 pa0 = mk8(w0, w1, w2, w3);
        const bf16x8 pa1 = mk8(w4, w5, w6, w7);

        const __hip_bfloat16* vt = Vt + (size_t)ktg * 2048 + lo5 * 32 + 8 * h;
        const bf16x8 va  = ldg8(vt);
        const bf16x8 vb2 = ldg8(vt + 16);
        const bf16x8 vc  = ldg8(vt + 1024);
        const bf16x8 vd  = ldg8(vt + 1024 + 16);
        __builtin_amdgcn_s_setprio(1);
        o0 = __builtin_amdgcn_mfma_f32_32x32x16_bf16(pa0, va,  o0, 0, 0, 0);
        o0 = __builtin_amdgcn_mfma_f32_32x32x16_bf16(pa1, vb2, o0, 0, 0, 0);
        o1 = __builtin_amdgcn_mfma_f32_32x32x16_bf16(pa0, vc,  o1, 0, 0, 0);
        o1 = __builtin_amdgcn_mfma_f32_32x32x16_bf16(pa1, vd,  o1, 0, 0, 0);
        __builtin_amdgcn_s_setprio(0);
    }

    // balanced reduction
    #pragma unroll
    for (int r = 0; r < 16; ++r) {
        red[w][r][l]      = o0[r];
        red[w][16 + r][l] = o1[r];
    }
    __syncthreads();

    {
        const int rr = t >> 4;            // 0..31
        const int l0 = (t & 15) * 4;      // 0..60
        float4 s = make_float4(0.f, 0.f, 0.f, 0.f);
        #pragma unroll
        for (int p = 0; p < 8; ++p) {
            const float4 v = *reinterpret_cast<const float4*>(&red[p][rr][l0]);
            s.x += v.x; s.y += v.y; s.z += v.z; s.w += v.w;
        }
        const int r   = rr & 15;
        const int row = (r & 3) + 8 * (r >> 2) + 4 * (l0 >> 5);
        if (rr < 16) {
            *reinterpret_cast<float4*>(
                &out[((size_t)(b * SEQ) + q0 + row) * HD + (l0 & 31)]) = s;
        } else if ((l0 & 31) < 16) {
            *reinterpret_cast<float4*>(
                &out[((size_t)(b * SEQ) + q0 + row) * HD + 32 + (l0 & 31)]) = s;
        }
    }
}

// ---------------------------------------------------------------------------
extern "C" void kernel_launch(void* const* d_in, const int* in_sizes, int n_in,
                              void* d_out, int out_size, void* d_ws, size_t ws_size,
                              hipStream_t stream)
{
    const float* x  = (const float*)d_in[0];
    const float* Wq = (const float*)d_in[1];
    const float* bq = (const float*)d_in[2];
    const float* Wk = (const float*)d_in[3];
    const float* bk = (const float*)d_in[4];
    const float* Wv = (const float*)d_in[5];
    const float* bv = (const float*)d_in[6];
    float* out = (float*)d_out;

    const size_t FRAG = (size_t)512 * 6 * 256;                     // 786432 elems
    __hip_bfloat16* Qf  = (__hip_bfloat16*)d_ws;                   // 1.5 MB
    __hip_bfloat16* Kf  = Qf + FRAG;                               // 1.5 MB
    float*          Vf  = (float*)(Kf + FRAG);                     // 3 MB
    __hip_bfloat16* Vt  = (__hip_bfloat16*)(Vf + (size_t)NB * SEQ * HD); // 2 MB
    __hip_bfloat16* Wf  = Vt + (size_t)NB * 128 * 2048;            // 240 KB
    float*          bias = (float*)(Wf + (size_t)5 * 48 * 512);    // 640 B

    prep_kernel<<<dim3(60), 256, 0, stream>>>(Wq, Wk, Wv, bq, bk, bv, Wf, bias);
    proj_kernel<<<dim3(512), 320, 0, stream>>>(x, Wf, bias, Qf, Kf, Vf);
    stats_kernel<<<dim3(128, NB), 512, 0, stream>>>(Qf, Kf, Vf, Vt);
    pv_kernel<<<dim3(128, NB), 512, 0, stream>>>(Qf, Kf, Vt, out);
}

// Round 8
// 68.188 us; speedup vs baseline: 1.0023x; 1.0023x over previous
//
#include <hip/hip_runtime.h>
#include <hip/hip_bf16.h>

#define NB 4
#define SEQ 4096
#define CDIM 768
#define HD 48

typedef __attribute__((ext_vector_type(8))) __bf16 bf16x8;
typedef __attribute__((ext_vector_type(16))) float f32x16;

// (1/sqrt(48)) * log2(e): folded into Q at projection store so P = exp2(S_acc)
static constexpr float SCALE_LOG2E = 0.20823542135164923f;

__device__ __forceinline__ bf16x8 ldg8(const __hip_bfloat16* p) {
    uint4 u = *reinterpret_cast<const uint4*>(p);
    bf16x8 r;
    __builtin_memcpy(&r, &u, 16);
    return r;
}
__device__ __forceinline__ unsigned pk2(float lo, float hi) {
    const __hip_bfloat16 a = __float2bfloat16(lo);
    const __hip_bfloat16 b = __float2bfloat16(hi);
    unsigned short ua, ub;
    __builtin_memcpy(&ua, &a, 2);
    __builtin_memcpy(&ub, &b, 2);
    return (unsigned)ua | ((unsigned)ub << 16);
}
__device__ __forceinline__ bf16x8 mk8(unsigned w0, unsigned w1, unsigned w2, unsigned w3) {
    const uint4 u = make_uint4(w0, w1, w2, w3);
    bf16x8 r;
    __builtin_memcpy(&r, &u, 16);
    return r;
}
// a,b -> a=[a.lo|b.lo], b=[a.hi|b.hi]  (swap a's upper 32 lanes with b's lower)
__device__ __forceinline__ void plswap(unsigned& a, unsigned& b) {
    asm volatile("v_permlane32_swap_b32 %0, %1" : "+v"(a), "+v"(b));
}
// Q/K fragment base offset (elements): frag (tile, s, h) is 256 contiguous bf16
__device__ __forceinline__ size_t fragOff(int tile, int s, int h) {
    return (((size_t)tile * 3 + s) * 2 + h) * 256;
}
// XCD-pinning remap: linear block id (0..511) -> (b, tile) so that batch b's
// blocks land on XCD pair {2b, 2b+1} (assumes xcd = id % 8 round-robin).
__device__ __forceinline__ void xcd_remap(int id, int& b, int& tile) {
    const int xcd  = id & 7;
    const int slot = id >> 3;          // 0..63
    b    = xcd >> 1;
    tile = (xcd & 1) * 64 + slot;      // 0..127
}

// ---------------------------------------------------------------------------
// Kernel 0: prep — Wf in B-fragment-major layout:
//   Wf[nt(5)][ks(48)][l(64)][8] bf16, elem (nt,ks,l,j) = W[ks*16+(l>>5)*8+j][nt*32+(l&31)]
//   cols: 0..47 = Wq, 48..95 = Wk, 96..143 = Wv, 144..159 = 0.  bias[160].
// ---------------------------------------------------------------------------
__global__ __launch_bounds__(256) void prep_kernel(
    const float* __restrict__ Wq, const float* __restrict__ Wk,
    const float* __restrict__ Wv,
    const float* __restrict__ bq, const float* __restrict__ bk,
    const float* __restrict__ bv,
    __hip_bfloat16* __restrict__ Wf, float* __restrict__ bias)
{
    const int g = blockIdx.x * 256 + threadIdx.x;   // 0..15359
    if (g < 15360) {
        const int rem  = g % 3072;
        const int nt   = g / 3072;
        const int ks   = rem >> 6;
        const int l2   = rem & 63;
        const int hh   = l2 >> 5;
        const int lane = l2 & 31;
        const int n    = nt * 32 + lane;
        const float* src = (n < 48) ? Wq : (n < 96) ? Wk : (n < 144) ? Wv : nullptr;
        const int col = (n < 48) ? n : (n < 96) ? (n - 48) : (n - 96);
        #pragma unroll
        for (int j = 0; j < 8; ++j) {
            const int k = ks * 16 + hh * 8 + j;
            const float wv = src ? src[(size_t)k * HD + col] : 0.0f;
            Wf[(size_t)g * 8 + j] = __float2bfloat16(wv);
        }
    }
    if (blockIdx.x == 0 && threadIdx.x < 160) {
        const int t = threadIdx.x;
        bias[t] = (t < 48) ? bq[t] : (t < 96) ? bk[t - 48] : (t < 144) ? bv[t - 96] : 0.0f;
    }
}

// ---------------------------------------------------------------------------
// Kernel 1: proj.  1 block per 32-row m-tile, 5 waves (wave = one 32-col n-tile).
// Stage x rows coalesced-along-k -> A-frag-major LDS (bf16), then
// 48 x { ds_read_b128 A + coalesced global B + MFMA }.
// ---------------------------------------------------------------------------
__global__ __launch_bounds__(320) void proj_kernel(
    const float* __restrict__ x,
    const __hip_bfloat16* __restrict__ Wf, const float* __restrict__ bias,
    __hip_bfloat16* __restrict__ Qf, __hip_bfloat16* __restrict__ Kf,
    float* __restrict__ Vf)
{
    __shared__ __hip_bfloat16 xs[48 * 512];   // [ks][l][8] frag-major, 48 KB

    const int t   = threadIdx.x;
    const int w   = t >> 6;          // wave = n-tile 0..4
    const int l   = t & 63;
    const int lo5 = l & 31, h = l >> 5;
    const int mt  = blockIdx.x;      // 0..511
    const int m0  = mt * 32;

    // stage: 32 rows x 768 k fp32 -> bf16 frag-major.  6144 float4 over 320 thr.
    const float* xb = x + (size_t)m0 * CDIM;
    #pragma unroll
    for (int i = 0; i < 20; ++i) {
        const int c = i * 320 + t;
        if (c < 6144) {
            const int r   = c / 192;
            const int pos = c % 192;
            const int k   = pos * 4;
            const float4 v = *reinterpret_cast<const float4*>(xb + (size_t)r * CDIM + k);
            const int ks = k >> 4, hh = (k >> 3) & 1, j = k & 7;
            const uint2 d = make_uint2(pk2(v.x, v.y), pk2(v.z, v.w));
            *reinterpret_cast<uint2*>(&xs[ks * 512 + (hh * 32 + r) * 8 + j]) = d;
        }
    }
    __syncthreads();

    const __hip_bfloat16* bp = Wf + (size_t)w * 24576 + l * 8;
    f32x16 acc = {};
    #pragma unroll 8
    for (int ks = 0; ks < 48; ++ks) {
        bf16x8 a;
        __builtin_memcpy(&a, &xs[ks * 512 + l * 8], 16);
        const bf16x8 b = ldg8(bp + (size_t)ks * 512);
        __builtin_amdgcn_s_setprio(1);
        acc = __builtin_amdgcn_mfma_f32_32x32x16_bf16(a, b, acc, 0, 0, 0);
        __builtin_amdgcn_s_setprio(0);
    }

    const int n_g = w * 32 + lo5;
    const float bs = bias[n_g];
    if (n_g < 96) {
        const bool isQ = (n_g < 48);
        const int d  = isQ ? n_g : n_g - 48;
        const int s  = d >> 4;
        const int hf = (d >> 3) & 1;
        __hip_bfloat16* base = (isQ ? Qf : Kf) + fragOff(mt, s, hf) + (d & 7);
        #pragma unroll
        for (int r = 0; r < 16; ++r) {
            const int mrow = (r & 3) + 8 * (r >> 2) + 4 * h;
            float val = acc[r] + bs;
            if (isQ) val *= SCALE_LOG2E;
            base[mrow * 8] = __float2bfloat16(val);
        }
    } else if (n_g < 144) {
        const int d = n_g - 96;
        #pragma unroll
        for (int r = 0; r < 16; ++r) {
            const int m = m0 + (r & 3) + 8 * (r >> 2) + 4 * h;
            Vf[(size_t)m * HD + d] = acc[r] + bs;
        }
    }
}

// ---------------------------------------------------------------------------
// Kernel 2: column softmax denominator + V fold.  8 waves split the q-range.
// Vt tiled [b][ktile][d(64)][32] bf16 = V[k][d] / l_k  (d<48 written only).
// XCD-pinned: batch b -> XCD pair {2b, 2b+1}.
// ---------------------------------------------------------------------------
__global__ __launch_bounds__(512) void stats_kernel(
    const __hip_bfloat16* __restrict__ Qf, const __hip_bfloat16* __restrict__ Kf,
    const float* __restrict__ Vf, __hip_bfloat16* __restrict__ Vt)
{
    __shared__ float part[8][32];
    __shared__ float linv[32];

    const int t   = threadIdx.x;
    const int w   = t >> 6;
    const int l   = t & 63;
    const int lo5 = l & 31, h = l >> 5;
    int b, ktile_l;
    xcd_remap(blockIdx.x + 128 * blockIdx.y, b, ktile_l);
    const int ktile = b * 128 + ktile_l;

    bf16x8 ka[3];
    #pragma unroll
    for (int s = 0; s < 3; ++s)
        ka[s] = ldg8(Kf + fragOff(ktile, s, h) + lo5 * 8);

    float lsum[16];
    #pragma unroll
    for (int r = 0; r < 16; ++r) lsum[r] = 0.0f;

    const int qt0 = b * 128 + w * 16;
    #pragma unroll 2
    for (int qq = 0; qq < 16; ++qq) {
        bf16x8 qb[3];
        #pragma unroll
        for (int s = 0; s < 3; ++s)
            qb[s] = ldg8(Qf + fragOff(qt0 + qq, s, h) + lo5 * 8);
        f32x16 acc = {};
        __builtin_amdgcn_s_setprio(1);
        #pragma unroll
        for (int s = 0; s < 3; ++s)
            acc = __builtin_amdgcn_mfma_f32_32x32x16_bf16(ka[s], qb[s], acc, 0, 0, 0);
        __builtin_amdgcn_s_setprio(0);
        #pragma unroll
        for (int r = 0; r < 16; ++r) lsum[r] += __builtin_amdgcn_exp2f(acc[r]);
    }

    #pragma unroll
    for (int r = 0; r < 16; ++r) {
        lsum[r] += __shfl_xor(lsum[r], 1);
        lsum[r] += __shfl_xor(lsum[r], 2);
        lsum[r] += __shfl_xor(lsum[r], 4);
        lsum[r] += __shfl_xor(lsum[r], 8);
        lsum[r] += __shfl_xor(lsum[r], 16);
    }
    if (lo5 == 0) {
        #pragma unroll
        for (int r = 0; r < 16; ++r)
            part[w][(r & 3) + 8 * (r >> 2) + 4 * h] = lsum[r];
    }
    __syncthreads();
    if (t < 32) {
        float s = 0.0f;
        #pragma unroll
        for (int p = 0; p < 8; ++p) s += part[p][t];
        linv[t] = 1.0f / s;
    }
    __syncthreads();

    // V fold: thread -> (k-pair kp, d = dg and dg+32 if dg<16)
    const int kp = t & 15;
    const int dg = t >> 4;          // 0..31
    const float f0 = linv[2 * kp], f1 = linv[2 * kp + 1];
    __hip_bfloat16* vtb = Vt + (size_t)ktile * 2048;
    const float* vfb = Vf + ((size_t)b * SEQ + ktile_l * 32 + 2 * kp) * HD;
    {
        const int d = dg;
        const float v0 = vfb[d], v1 = vfb[HD + d];
        *reinterpret_cast<unsigned*>(&vtb[d * 32 + 2 * kp]) = pk2(v0 * f0, v1 * f1);
    }
    if (dg < 16) {
        const int d = dg + 32;
        const float v0 = vfb[d], v1 = vfb[HD + d];
        *reinterpret_cast<unsigned*>(&vtb[d * 32 + 2 * kp]) = pk2(v0 * f0, v1 * f1);
    }
}

// ---------------------------------------------------------------------------
// Kernel 3: O[q,d] = sum_k exp2(Shat[q,k]) * Vt[d,k].  8 waves split k-range.
// Balanced reduction via LDS dump.  XCD-pinned like stats.
// ---------------------------------------------------------------------------
__global__ __launch_bounds__(512) void pv_kernel(
    const __hip_bfloat16* __restrict__ Qf, const __hip_bfloat16* __restrict__ Kf,
    const __hip_bfloat16* __restrict__ Vt, float* __restrict__ out)
{
    __shared__ float red[8][32][64];   // 64 KB

    const int t   = threadIdx.x;
    const int w   = t >> 6;
    const int l   = t & 63;
    const int lo5 = l & 31, h = l >> 5;
    int b, qtile_l;
    xcd_remap(blockIdx.x + 128 * blockIdx.y, b, qtile_l);
    const int qtile = b * 128 + qtile_l;
    const int q0    = qtile_l * 32;

    bf16x8 qb[3];
    #pragma unroll
    for (int s = 0; s < 3; ++s)
        qb[s] = ldg8(Qf + fragOff(qtile, s, h) + lo5 * 8);

    f32x16 o0 = {}, o1 = {};
    const int kt0 = b * 128 + w * 16;

    #pragma unroll 2
    for (int kk = 0; kk < 16; ++kk) {
        const int ktg = kt0 + kk;
        bf16x8 ka[3];
        #pragma unroll
        for (int s = 0; s < 3; ++s)
            ka[s] = ldg8(Kf + fragOff(ktg, s, h) + lo5 * 8);
        f32x16 acc = {};
        __builtin_amdgcn_s_setprio(1);
        #pragma unroll
        for (int s = 0; s < 3; ++s)
            acc = __builtin_amdgcn_mfma_f32_32x32x16_bf16(ka[s], qb[s], acc, 0, 0, 0);
        __builtin_amdgcn_s_setprio(0);

        float p[16];
        #pragma unroll
        for (int r = 0; r < 16; ++r) p[r] = __builtin_amdgcn_exp2f(acc[r]);

        // pack row-pairs then swap halves across lane 32 with permlane32_swap
        unsigned w0 = pk2(p[0],  p[1]),  w1 = pk2(p[2],  p[3]);
        unsigned w2 = pk2(p[4],  p[5]),  w3 = pk2(p[6],  p[7]);
        unsigned w4 = pk2(p[8],  p[9]),  w5 = pk2(p[10], p[11]);
        unsigned w6 = pk2(p[12], p[13]), w7 = pk2(p[14], p[15]);
        plswap(w0, w2);
        plswap(w1, w3);
        plswap(w4, w6);
        plswap(w5, w7);

        const bf16x8 pa0 = mk8(w0, w1, w2, w3);
        const bf16x8 pa1 = mk8(w4, w5, w6, w7);

        const __hip_bfloat16* vt = Vt + (size_t)ktg * 2048 + lo5 * 32 + 8 * h;
        const bf16x8 va  = ldg8(vt);
        const bf16x8 vb2 = ldg8(vt + 16);
        const bf16x8 vc  = ldg8(vt + 1024);
        const bf16x8 vd  = ldg8(vt + 1024 + 16);
        __builtin_amdgcn_s_setprio(1);
        o0 = __builtin_amdgcn_mfma_f32_32x32x16_bf16(pa0, va,  o0, 0, 0, 0);
        o0 = __builtin_amdgcn_mfma_f32_32x32x16_bf16(pa1, vb2, o0, 0, 0, 0);
        o1 = __builtin_amdgcn_mfma_f32_32x32x16_bf16(pa0, vc,  o1, 0, 0, 0);
        o1 = __builtin_amdgcn_mfma_f32_32x32x16_bf16(pa1, vd,  o1, 0, 0, 0);
        __builtin_amdgcn_s_setprio(0);
    }

    // balanced reduction
    #pragma unroll
    for (int r = 0; r < 16; ++r) {
        red[w][r][l]      = o0[r];
        red[w][16 + r][l] = o1[r];
    }
    __syncthreads();

    {
        const int rr = t >> 4;            // 0..31
        const int l0 = (t & 15) * 4;      // 0..60
        float4 s = make_float4(0.f, 0.f, 0.f, 0.f);
        #pragma unroll
        for (int p = 0; p < 8; ++p) {
            const float4 v = *reinterpret_cast<const float4*>(&red[p][rr][l0]);
            s.x += v.x; s.y += v.y; s.z += v.z; s.w += v.w;
        }
        const int r   = rr & 15;
        const int row = (r & 3) + 8 * (r >> 2) + 4 * (l0 >> 5);
        if (rr < 16) {
            *reinterpret_cast<float4*>(
                &out[((size_t)(b * SEQ) + q0 + row) * HD + (l0 & 31)]) = s;
        } else if ((l0 & 31) < 16) {
            *reinterpret_cast<float4*>(
                &out[((size_t)(b * SEQ) + q0 + row) * HD + 32 + (l0 & 31)]) = s;
        }
    }
}

// ---------------------------------------------------------------------------
extern "C" void kernel_launch(void* const* d_in, const int* in_sizes, int n_in,
                              void* d_out, int out_size, void* d_ws, size_t ws_size,
                              hipStream_t stream)
{
    const float* x  = (const float*)d_in[0];
    const float* Wq = (const float*)d_in[1];
    const float* bq = (const float*)d_in[2];
    const float* Wk = (const float*)d_in[3];
    const float* bk = (const float*)d_in[4];
    const float* Wv = (const float*)d_in[5];
    const float* bv = (const float*)d_in[6];
    float* out = (float*)d_out;

    const size_t FRAG = (size_t)512 * 6 * 256;                     // 786432 elems
    __hip_bfloat16* Qf  = (__hip_bfloat16*)d_ws;                   // 1.5 MB
    __hip_bfloat16* Kf  = Qf + FRAG;                               // 1.5 MB
    float*          Vf  = (float*)(Kf + FRAG);                     // 3 MB
    __hip_bfloat16* Vt  = (__hip_bfloat16*)(Vf + (size_t)NB * SEQ * HD); // 2 MB
    __hip_bfloat16* Wf  = Vt + (size_t)NB * 128 * 2048;            // 240 KB
    float*          bias = (float*)(Wf + (size_t)5 * 48 * 512);    // 640 B

    prep_kernel<<<dim3(60), 256, 0, stream>>>(Wq, Wk, Wv, bq, bk, bv, Wf, bias);
    proj_kernel<<<dim3(512), 320, 0, stream>>>(x, Wf, bias, Qf, Kf, Vf);
    stats_kernel<<<dim3(128, NB), 512, 0, stream>>>(Qf, Kf, Vf, Vt);
    pv_kernel<<<dim3(128, NB), 512, 0, stream>>>(Qf, Kf, Vt, out);
}

// Round 9
// 65.505 us; speedup vs baseline: 1.0434x; 1.0410x over previous
//
#include <hip/hip_runtime.h>
#include <hip/hip_bf16.h>

#define NB 4
#define SEQ 4096
#define CDIM 768
#define HD 48

typedef __attribute__((ext_vector_type(8))) __bf16 bf16x8;
typedef __attribute__((ext_vector_type(16))) float f32x16;

// (1/sqrt(48)) * log2(e): folded into Q at projection store so P = exp2(S_acc)
static constexpr float SCALE_LOG2E = 0.20823542135164923f;

__device__ __forceinline__ bf16x8 ldg8(const __hip_bfloat16* p) {
    uint4 u = *reinterpret_cast<const uint4*>(p);
    bf16x8 r;
    __builtin_memcpy(&r, &u, 16);
    return r;
}
__device__ __forceinline__ unsigned pk2(float lo, float hi) {
    const __hip_bfloat16 a = __float2bfloat16(lo);
    const __hip_bfloat16 b = __float2bfloat16(hi);
    unsigned short ua, ub;
    __builtin_memcpy(&ua, &a, 2);
    __builtin_memcpy(&ub, &b, 2);
    return (unsigned)ua | ((unsigned)ub << 16);
}
__device__ __forceinline__ bf16x8 mk8(unsigned w0, unsigned w1, unsigned w2, unsigned w3) {
    const uint4 u = make_uint4(w0, w1, w2, w3);
    bf16x8 r;
    __builtin_memcpy(&r, &u, 16);
    return r;
}
// a,b -> a=[a.lo|b.lo], b=[a.hi|b.hi]
__device__ __forceinline__ void plswap(unsigned& a, unsigned& b) {
    asm volatile("v_permlane32_swap_b32 %0, %1" : "+v"(a), "+v"(b));
}
// Q/K fragment base offset (elements): frag (tile, s, h) is 256 contiguous bf16
__device__ __forceinline__ size_t fragOff(int tile, int s, int h) {
    return (((size_t)tile * 3 + s) * 2 + h) * 256;
}
// 256-block remap: batch b -> XCD pair {2b,2b+1}; 64 supertiles per batch
__device__ __forceinline__ void xcd_remap64(int id, int& b, int& st) {
    const int xcd = id & 7;
    b  = xcd >> 1;
    st = (xcd & 1) * 32 + (id >> 3);   // 0..63
}

// ---------------------------------------------------------------------------
// Kernel 0: prep — Wf in B-fragment-major layout (see R6).  bias[160].
// ---------------------------------------------------------------------------
__global__ __launch_bounds__(256) void prep_kernel(
    const float* __restrict__ Wq, const float* __restrict__ Wk,
    const float* __restrict__ Wv,
    const float* __restrict__ bq, const float* __restrict__ bk,
    const float* __restrict__ bv,
    __hip_bfloat16* __restrict__ Wf, float* __restrict__ bias)
{
    const int g = blockIdx.x * 256 + threadIdx.x;   // 0..15359
    if (g < 15360) {
        const int rem  = g % 3072;
        const int nt   = g / 3072;
        const int ks   = rem >> 6;
        const int l2   = rem & 63;
        const int hh   = l2 >> 5;
        const int lane = l2 & 31;
        const int n    = nt * 32 + lane;
        const float* src = (n < 48) ? Wq : (n < 96) ? Wk : (n < 144) ? Wv : nullptr;
        const int col = (n < 48) ? n : (n < 96) ? (n - 48) : (n - 96);
        #pragma unroll
        for (int j = 0; j < 8; ++j) {
            const int k = ks * 16 + hh * 8 + j;
            const float wv = src ? src[(size_t)k * HD + col] : 0.0f;
            Wf[(size_t)g * 8 + j] = __float2bfloat16(wv);
        }
    }
    if (blockIdx.x == 0 && threadIdx.x < 160) {
        const int t = threadIdx.x;
        bias[t] = (t < 48) ? bq[t] : (t < 96) ? bk[t - 48] : (t < 144) ? bv[t - 96] : 0.0f;
    }
}

// ---------------------------------------------------------------------------
// Kernel 1: proj (unchanged from R6).  1 block per 32-row m-tile, 5 waves.
// ---------------------------------------------------------------------------
__global__ __launch_bounds__(320) void proj_kernel(
    const float* __restrict__ x,
    const __hip_bfloat16* __restrict__ Wf, const float* __restrict__ bias,
    __hip_bfloat16* __restrict__ Qf, __hip_bfloat16* __restrict__ Kf,
    float* __restrict__ Vf)
{
    __shared__ __hip_bfloat16 xs[48 * 512];   // 48 KB

    const int t   = threadIdx.x;
    const int w   = t >> 6;
    const int l   = t & 63;
    const int lo5 = l & 31, h = l >> 5;
    const int mt  = blockIdx.x;
    const int m0  = mt * 32;

    const float* xb = x + (size_t)m0 * CDIM;
    #pragma unroll
    for (int i = 0; i < 20; ++i) {
        const int c = i * 320 + t;
        if (c < 6144) {
            const int r   = c / 192;
            const int pos = c % 192;
            const int k   = pos * 4;
            const float4 v = *reinterpret_cast<const float4*>(xb + (size_t)r * CDIM + k);
            const int ks = k >> 4, hh = (k >> 3) & 1, j = k & 7;
            const uint2 d = make_uint2(pk2(v.x, v.y), pk2(v.z, v.w));
            *reinterpret_cast<uint2*>(&xs[ks * 512 + (hh * 32 + r) * 8 + j]) = d;
        }
    }
    __syncthreads();

    const __hip_bfloat16* bp = Wf + (size_t)w * 24576 + l * 8;
    f32x16 acc = {};
    #pragma unroll 8
    for (int ks = 0; ks < 48; ++ks) {
        bf16x8 a;
        __builtin_memcpy(&a, &xs[ks * 512 + l * 8], 16);
        const bf16x8 b = ldg8(bp + (size_t)ks * 512);
        __builtin_amdgcn_s_setprio(1);
        acc = __builtin_amdgcn_mfma_f32_32x32x16_bf16(a, b, acc, 0, 0, 0);
        __builtin_amdgcn_s_setprio(0);
    }

    const int n_g = w * 32 + lo5;
    const float bs = bias[n_g];
    if (n_g < 96) {
        const bool isQ = (n_g < 48);
        const int d  = isQ ? n_g : n_g - 48;
        const int s  = d >> 4;
        const int hf = (d >> 3) & 1;
        __hip_bfloat16* base = (isQ ? Qf : Kf) + fragOff(mt, s, hf) + (d & 7);
        #pragma unroll
        for (int r = 0; r < 16; ++r) {
            const int mrow = (r & 3) + 8 * (r >> 2) + 4 * h;
            float val = acc[r] + bs;
            if (isQ) val *= SCALE_LOG2E;
            base[mrow * 8] = __float2bfloat16(val);
        }
    } else if (n_g < 144) {
        const int d = n_g - 96;
        #pragma unroll
        for (int r = 0; r < 16; ++r) {
            const int m = m0 + (r & 3) + 8 * (r >> 2) + 4 * h;
            Vf[(size_t)m * HD + d] = acc[r] + bs;
        }
    }
}

// ---------------------------------------------------------------------------
// Kernel 2: stats, 64-k blocks (2 k-tiles share each Q-fragment load).
// 256 blocks, 8 waves split the q-range (16 q-tiles each).
// ---------------------------------------------------------------------------
__global__ __launch_bounds__(512, 2) void stats_kernel(
    const __hip_bfloat16* __restrict__ Qf, const __hip_bfloat16* __restrict__ Kf,
    const float* __restrict__ Vf, __hip_bfloat16* __restrict__ Vt)
{
    __shared__ float part[8][64];
    __shared__ float linv[64];

    const int t   = threadIdx.x;
    const int w   = t >> 6;
    const int l   = t & 63;
    const int lo5 = l & 31, h = l >> 5;
    int b, kst;
    xcd_remap64(blockIdx.x, b, kst);
    const int ktile0 = b * 128 + kst * 2;

    bf16x8 ka[6];
    #pragma unroll
    for (int s = 0; s < 3; ++s) {
        ka[s]     = ldg8(Kf + fragOff(ktile0,     s, h) + lo5 * 8);
        ka[3 + s] = ldg8(Kf + fragOff(ktile0 + 1, s, h) + lo5 * 8);
    }

    float lsum[32];
    #pragma unroll
    for (int r = 0; r < 32; ++r) lsum[r] = 0.0f;

    const int qt0 = b * 128 + w * 16;
    #pragma unroll 2
    for (int qq = 0; qq < 16; ++qq) {
        bf16x8 qb[3];
        #pragma unroll
        for (int s = 0; s < 3; ++s)
            qb[s] = ldg8(Qf + fragOff(qt0 + qq, s, h) + lo5 * 8);
        f32x16 a0 = {}, a1 = {};
        __builtin_amdgcn_s_setprio(1);
        #pragma unroll
        for (int s = 0; s < 3; ++s)
            a0 = __builtin_amdgcn_mfma_f32_32x32x16_bf16(ka[s], qb[s], a0, 0, 0, 0);
        #pragma unroll
        for (int s = 0; s < 3; ++s)
            a1 = __builtin_amdgcn_mfma_f32_32x32x16_bf16(ka[3 + s], qb[s], a1, 0, 0, 0);
        __builtin_amdgcn_s_setprio(0);
        #pragma unroll
        for (int r = 0; r < 16; ++r) {
            lsum[r]      += __builtin_amdgcn_exp2f(a0[r]);
            lsum[16 + r] += __builtin_amdgcn_exp2f(a1[r]);
        }
    }

    #pragma unroll
    for (int r = 0; r < 32; ++r) {
        lsum[r] += __shfl_xor(lsum[r], 1);
        lsum[r] += __shfl_xor(lsum[r], 2);
        lsum[r] += __shfl_xor(lsum[r], 4);
        lsum[r] += __shfl_xor(lsum[r], 8);
        lsum[r] += __shfl_xor(lsum[r], 16);
    }
    if (lo5 == 0) {
        #pragma unroll
        for (int r = 0; r < 16; ++r) {
            const int row = (r & 3) + 8 * (r >> 2) + 4 * h;
            part[w][row]      = lsum[r];
            part[w][32 + row] = lsum[16 + r];
        }
    }
    __syncthreads();
    if (t < 64) {
        float s = 0.0f;
        #pragma unroll
        for (int p = 0; p < 8; ++p) s += part[p][t];
        linv[t] = 1.0f / s;
    }
    __syncthreads();

    // V fold for both tiles: thread -> (k-pair kp, d = dg and dg+32 if dg<16)
    const int kp = t & 15;
    const int dg = t >> 4;          // 0..31
    #pragma unroll
    for (int tt = 0; tt < 2; ++tt) {
        const int ktile = ktile0 + tt;
        const float f0 = linv[tt * 32 + 2 * kp], f1 = linv[tt * 32 + 2 * kp + 1];
        __hip_bfloat16* vtb = Vt + (size_t)ktile * 2048;
        const float* vfb = Vf + ((size_t)b * SEQ + (kst * 2 + tt) * 32 + 2 * kp) * HD;
        {
            const int d = dg;
            const float v0 = vfb[d], v1 = vfb[HD + d];
            *reinterpret_cast<unsigned*>(&vtb[d * 32 + 2 * kp]) = pk2(v0 * f0, v1 * f1);
        }
        if (dg < 16) {
            const int d = dg + 32;
            const float v0 = vfb[d], v1 = vfb[HD + d];
            *reinterpret_cast<unsigned*>(&vtb[d * 32 + 2 * kp]) = pk2(v0 * f0, v1 * f1);
        }
    }
}

// ---------------------------------------------------------------------------
// Kernel 3: pv, 64-q blocks (2 q-tiles share each K/V-fragment load).
// 256 blocks, 8 waves split k-range; two-round LDS reduction (64 KB).
// ---------------------------------------------------------------------------
__global__ __launch_bounds__(512, 2) void pv_kernel(
    const __hip_bfloat16* __restrict__ Qf, const __hip_bfloat16* __restrict__ Kf,
    const __hip_bfloat16* __restrict__ Vt, float* __restrict__ out)
{
    __shared__ float red[8][32][64];   // 64 KB

    const int t   = threadIdx.x;
    const int w   = t >> 6;
    const int l   = t & 63;
    const int lo5 = l & 31, h = l >> 5;
    int b, qst;
    xcd_remap64(blockIdx.x, b, qst);
    const int qtile0 = b * 128 + qst * 2;
    const int q0     = qst * 64;

    bf16x8 qb[6];
    #pragma unroll
    for (int s = 0; s < 3; ++s) {
        qb[s]     = ldg8(Qf + fragOff(qtile0,     s, h) + lo5 * 8);
        qb[3 + s] = ldg8(Qf + fragOff(qtile0 + 1, s, h) + lo5 * 8);
    }

    f32x16 o00 = {}, o01 = {}, o10 = {}, o11 = {};
    const int kt0 = b * 128 + w * 16;

    #pragma unroll 2
    for (int kk = 0; kk < 16; ++kk) {
        const int ktg = kt0 + kk;
        bf16x8 ka[3];
        #pragma unroll
        for (int s = 0; s < 3; ++s)
            ka[s] = ldg8(Kf + fragOff(ktg, s, h) + lo5 * 8);
        const __hip_bfloat16* vt = Vt + (size_t)ktg * 2048 + lo5 * 32 + 8 * h;
        const bf16x8 va  = ldg8(vt);
        const bf16x8 vb2 = ldg8(vt + 16);
        const bf16x8 vc  = ldg8(vt + 1024);
        const bf16x8 vd  = ldg8(vt + 1024 + 16);

        #pragma unroll
        for (int qt = 0; qt < 2; ++qt) {
            f32x16 acc = {};
            __builtin_amdgcn_s_setprio(1);
            #pragma unroll
            for (int s = 0; s < 3; ++s)
                acc = __builtin_amdgcn_mfma_f32_32x32x16_bf16(
                    ka[s], qb[3 * qt + s], acc, 0, 0, 0);
            __builtin_amdgcn_s_setprio(0);

            float p[16];
            #pragma unroll
            for (int r = 0; r < 16; ++r) p[r] = __builtin_amdgcn_exp2f(acc[r]);

            unsigned w0 = pk2(p[0],  p[1]),  w1 = pk2(p[2],  p[3]);
            unsigned w2 = pk2(p[4],  p[5]),  w3 = pk2(p[6],  p[7]);
            unsigned w4 = pk2(p[8],  p[9]),  w5 = pk2(p[10], p[11]);
            unsigned w6 = pk2(p[12], p[13]), w7 = pk2(p[14], p[15]);
            plswap(w0, w2);
            plswap(w1, w3);
            plswap(w4, w6);
            plswap(w5, w7);
            const bf16x8 pa0 = mk8(w0, w1, w2, w3);
            const bf16x8 pa1 = mk8(w4, w5, w6, w7);

            __builtin_amdgcn_s_setprio(1);
            if (qt == 0) {
                o00 = __builtin_amdgcn_mfma_f32_32x32x16_bf16(pa0, va,  o00, 0, 0, 0);
                o00 = __builtin_amdgcn_mfma_f32_32x32x16_bf16(pa1, vb2, o00, 0, 0, 0);
                o01 = __builtin_amdgcn_mfma_f32_32x32x16_bf16(pa0, vc,  o01, 0, 0, 0);
                o01 = __builtin_amdgcn_mfma_f32_32x32x16_bf16(pa1, vd,  o01, 0, 0, 0);
            } else {
                o10 = __builtin_amdgcn_mfma_f32_32x32x16_bf16(pa0, va,  o10, 0, 0, 0);
                o10 = __builtin_amdgcn_mfma_f32_32x32x16_bf16(pa1, vb2, o10, 0, 0, 0);
                o11 = __builtin_amdgcn_mfma_f32_32x32x16_bf16(pa0, vc,  o11, 0, 0, 0);
                o11 = __builtin_amdgcn_mfma_f32_32x32x16_bf16(pa1, vd,  o11, 0, 0, 0);
            }
            __builtin_amdgcn_s_setprio(0);
        }
    }

    // two-round balanced reduction (q-tile 0 then q-tile 1)
    #pragma unroll
    for (int round = 0; round < 2; ++round) {
        const f32x16& a = round ? o10 : o00;
        const f32x16& c = round ? o11 : o01;
        #pragma unroll
        for (int r = 0; r < 16; ++r) {
            red[w][r][l]      = a[r];
            red[w][16 + r][l] = c[r];
        }
        __syncthreads();
        {
            const int rr = t >> 4;            // 0..31
            const int l0 = (t & 15) * 4;      // 0..60
            float4 s = make_float4(0.f, 0.f, 0.f, 0.f);
            #pragma unroll
            for (int p = 0; p < 8; ++p) {
                const float4 v = *reinterpret_cast<const float4*>(&red[p][rr][l0]);
                s.x += v.x; s.y += v.y; s.z += v.z; s.w += v.w;
            }
            const int r    = rr & 15;
            const int row  = (r & 3) + 8 * (r >> 2) + 4 * (l0 >> 5);
            const int qrow = q0 + round * 32 + row;
            if (rr < 16) {
                *reinterpret_cast<float4*>(
                    &out[((size_t)(b * SEQ) + qrow) * HD + (l0 & 31)]) = s;
            } else if ((l0 & 31) < 16) {
                *reinterpret_cast<float4*>(
                    &out[((size_t)(b * SEQ) + qrow) * HD + 32 + (l0 & 31)]) = s;
            }
        }
        __syncthreads();
    }
}

// ---------------------------------------------------------------------------
extern "C" void kernel_launch(void* const* d_in, const int* in_sizes, int n_in,
                              void* d_out, int out_size, void* d_ws, size_t ws_size,
                              hipStream_t stream)
{
    const float* x  = (const float*)d_in[0];
    const float* Wq = (const float*)d_in[1];
    const float* bq = (const float*)d_in[2];
    const float* Wk = (const float*)d_in[3];
    const float* bk = (const float*)d_in[4];
    const float* Wv = (const float*)d_in[5];
    const float* bv = (const float*)d_in[6];
    float* out = (float*)d_out;

    const size_t FRAG = (size_t)512 * 6 * 256;                     // 786432 elems
    __hip_bfloat16* Qf  = (__hip_bfloat16*)d_ws;                   // 1.5 MB
    __hip_bfloat16* Kf  = Qf + FRAG;                               // 1.5 MB
    float*          Vf  = (float*)(Kf + FRAG);                     // 3 MB
    __hip_bfloat16* Vt  = (__hip_bfloat16*)(Vf + (size_t)NB * SEQ * HD); // 2 MB
    __hip_bfloat16* Wf  = Vt + (size_t)NB * 128 * 2048;            // 240 KB
    float*          bias = (float*)(Wf + (size_t)5 * 48 * 512);    // 640 B

    prep_kernel<<<dim3(60), 256, 0, stream>>>(Wq, Wk, Wv, bq, bk, bv, Wf, bias);
    proj_kernel<<<dim3(512), 320, 0, stream>>>(x, Wf, bias, Qf, Kf, Vf);
    stats_kernel<<<dim3(256), 512, 0, stream>>>(Qf, Kf, Vf, Vt);
    pv_kernel<<<dim3(256), 512, 0, stream>>>(Qf, Kf, Vt, out);
}